// Round 1
// baseline (589.428 us; speedup 1.0000x reference)
//
#include <hip/hip_runtime.h>
#include <hip/hip_bf16.h>
#include <stdint.h>

#define N_TOK 4096
#define DIM   1024
#define NE    8
#define HID   4096
#define OUTD  1024
#define TOPK  2
#define SLOTS (N_TOK*TOPK)
#define SLOTS_PAD (SLOTS+128)

typedef __bf16 bf16_t;
typedef __attribute__((ext_vector_type(8))) __bf16 bf16x8;
typedef __attribute__((ext_vector_type(4))) __bf16 bf16x4;
typedef __attribute__((ext_vector_type(4))) float  f32x4;

// ---------------- gating: logits in fp64, top-2, softmax ----------------
__global__ void k_gating(const float* __restrict__ x, const float* __restrict__ wg,
                         int* __restrict__ tki, float* __restrict__ tkg,
                         int* __restrict__ counts) {
    int n = blockIdx.x;
    int lane = threadIdx.x;            // 64 threads
    double acc[NE];
#pragma unroll
    for (int e = 0; e < NE; ++e) acc[e] = 0.0;
    const float* xr = x + (size_t)n * DIM;
    for (int d = lane; d < DIM; d += 64) {
        double xv = (double)xr[d];
        const float* wr = wg + (size_t)d * NE;
#pragma unroll
        for (int e = 0; e < NE; ++e) acc[e] += xv * (double)wr[e];
    }
#pragma unroll
    for (int e = 0; e < NE; ++e)
        for (int off = 32; off > 0; off >>= 1) acc[e] += __shfl_xor(acc[e], off);
    if (lane == 0) {
        int i0 = 0; double v0 = acc[0];
#pragma unroll
        for (int e = 1; e < NE; ++e) if (acc[e] > v0) { v0 = acc[e]; i0 = e; }
        int i1 = -1; double v1 = -1e300;
#pragma unroll
        for (int e = 0; e < NE; ++e) if (e != i0 && acc[e] > v1) { v1 = acc[e]; i1 = e; }
        double e1 = exp(v1 - v0);
        double s = 1.0 + e1;
        tki[n*2]   = i0;  tki[n*2+1] = i1;
        tkg[n*2]   = (float)(1.0 / s);
        tkg[n*2+1] = (float)(e1 / s);
        atomicAdd(&counts[i0], 1);
        atomicAdd(&counts[i1], 1);
    }
}

// ---------------- importance: deterministic per-expert reduction ----------------
__global__ void k_importance(const int* __restrict__ tki, const float* __restrict__ tkg,
                             float* __restrict__ imp) {
    int e = blockIdx.x, t = threadIdx.x;
    __shared__ float red[256];
    float s = 0.f;
    for (int i = t; i < SLOTS; i += 256) s += (tki[i] == e) ? tkg[i] : 0.f;
    red[t] = s; __syncthreads();
    for (int off = 128; off > 0; off >>= 1) {
        if (t < off) red[t] += red[t + off];
        __syncthreads();
    }
    if (t == 0) imp[e] = red[0];
}

// ---------------- aux loss + prefix-sum bases ----------------
__global__ void k_finalize(const float* __restrict__ imp, const int* __restrict__ counts,
                           int* __restrict__ bases, float* __restrict__ aux_out) {
    if (threadIdx.x == 0 && blockIdx.x == 0) {
        float m = 0.f;
        for (int e = 0; e < NE; ++e) m += imp[e];
        m /= (float)NE;
        float var = 0.f;
        for (int e = 0; e < NE; ++e) { float d = imp[e] - m; var += d * d; }
        var /= (float)NE;
        aux_out[0] = 0.01f * var / (m * m + 1e-10f);
        int b = 0;
        for (int e = 0; e < NE; ++e) { bases[e] = b; b += counts[e]; }
    }
}

// ---------------- build per-expert token lists ----------------
__global__ void k_build(const int* __restrict__ tki, const float* __restrict__ tkg,
                        const int* __restrict__ bases, int* __restrict__ cursor,
                        int* __restrict__ tok_ids, float* __restrict__ sgate) {
    int i = blockIdx.x * 256 + threadIdx.x;
    if (i < SLOTS) {
        int e = tki[i];
        int p = atomicAdd(&cursor[e], 1);
        int s = bases[e] + p;
        tok_ids[s] = i >> 1;
        sgate[s]   = tkg[i];
    }
}

// ---------------- x fp32 -> bf16 ----------------
__global__ void k_cast_x(const float* __restrict__ x, bf16_t* __restrict__ xb) {
    int i = (blockIdx.x * 256 + threadIdx.x) * 4;
    float4 v = *(const float4*)(x + i);
    bf16x4 o;
    o[0] = (__bf16)v.x; o[1] = (__bf16)v.y; o[2] = (__bf16)v.z; o[3] = (__bf16)v.w;
    *(bf16x4*)(xb + i) = o;
}

// ---------------- W [E][R][C] fp32 -> Wt [E][C][R] bf16 (LDS tiled) ----------------
__global__ void k_transpose(const float* __restrict__ src, bf16_t* __restrict__ dst,
                            int R, int C) {
    __shared__ float tile[32][33];
    const size_t slab = (size_t)R * C;
    const float* s = src + slab * blockIdx.z;
    bf16_t*      d = dst + slab * blockIdx.z;
    int c0 = blockIdx.x * 32, r0 = blockIdx.y * 32;
#pragma unroll
    for (int ss = 0; ss < 32; ss += 8)
        tile[threadIdx.y + ss][threadIdx.x] =
            s[(size_t)(r0 + threadIdx.y + ss) * C + c0 + threadIdx.x];
    __syncthreads();
#pragma unroll
    for (int ss = 0; ss < 32; ss += 8)
        d[(size_t)(c0 + threadIdx.y + ss) * R + r0 + threadIdx.x] =
            (__bf16)tile[threadIdx.x][threadIdx.y + ss];
}

// ---------------- grouped GEMM, 128x128 tile, BK=32, 4 waves ----------------
// MODE 0: h = relu(x_gather @ W1t^T + b1) -> hbuf (bf16)
// MODE 1: out[token] += gate * (h @ W2t^T + b2)  (atomic, exactly 2 adds/elem)
template <int MODE>
__global__ __launch_bounds__(256, 2)
void k_gemm(const bf16_t* __restrict__ A,    // MODE0: xb [N][DIM]; MODE1: hbuf [SLOTS_PAD][HID]
            const bf16_t* __restrict__ Bt,   // MODE0: w1t [E][HID][DIM]; MODE1: w2t [E][OUTD][HID]
            const float* __restrict__ bias,  // MODE0: b1 [E][HID]; MODE1: b2 [E][OUTD]
            const int* __restrict__ tok_ids,
            const float* __restrict__ sgate,
            const int* __restrict__ bases,
            const int* __restrict__ counts,
            bf16_t* __restrict__ hbuf,
            float* __restrict__ out) {
    constexpr int KD = (MODE == 0) ? DIM : HID;   // K length
    constexpr int ND = (MODE == 0) ? HID : OUTD;  // B-row count
    const int e  = blockIdx.z;
    const int ne = counts[e];
    const int m0 = blockIdx.y * 128;
    if (m0 >= ne) return;
    const int n0 = blockIdx.x * 128;
    const int b0 = bases[e];

    __shared__ bf16_t lA[128 * 32];  // 8 KB, XOR-swizzled slots
    __shared__ bf16_t lB[128 * 32];  // 8 KB

    const int t    = threadIdx.x;
    const int wave = t >> 6, lane = t & 63;
    const int wm = wave >> 1, wn = wave & 1;
    const int lr = lane & 15, lq = lane >> 4;

    // --- staging setup: waves 0-1 stage A rows, waves 2-3 stage Bt rows ---
    const int tilesel = wave >> 1;
    const int half    = wave & 1;
    const bf16_t* gsrc[4];
    bf16_t*       ldst[4];
#pragma unroll
    for (int p = 0; p < 4; ++p) {
        int row  = half * 64 + p * 16 + (lane >> 2);
        int slot = lane & 3;
        int g    = slot ^ ((row >> 1) & 3);   // logical k-group stored at this physical slot
        if (tilesel == 0) {
            size_t arow;
            if (MODE == 0) {
                int mm  = m0 + row;
                int tok = tok_ids[b0 + (mm < ne ? mm : 0)];
                arow = (size_t)tok * KD;
            } else {
                arow = (size_t)(b0 + m0 + row) * KD;
            }
            gsrc[p] = A + arow + g * 8;
            ldst[p] = lA + (half * 64 + p * 16) * 32;   // wave-uniform base
        } else {
            gsrc[p] = Bt + ((size_t)e * ND + n0 + row) * KD + g * 8;
            ldst[p] = lB + (half * 64 + p * 16) * 32;
        }
    }

    // --- LDS fragment read pointers (fixed across k-loop) ---
    const bf16_t* pA[4];
    const bf16_t* pB[4];
#pragma unroll
    for (int i = 0; i < 4; ++i) {
        int r = wm * 64 + i * 16 + lr;
        pA[i] = lA + r * 32 + ((lq ^ ((r >> 1) & 3)) << 3);
    }
#pragma unroll
    for (int j = 0; j < 4; ++j) {
        int r = wn * 64 + j * 16 + lr;
        pB[j] = lB + r * 32 + ((lq ^ ((r >> 1) & 3)) << 3);
    }

    f32x4 acc[4][4];
#pragma unroll
    for (int i = 0; i < 4; ++i)
#pragma unroll
        for (int j = 0; j < 4; ++j) acc[i][j] = (f32x4){0.f, 0.f, 0.f, 0.f};

    constexpr int KT = KD / 32;
    for (int kt = 0; kt < KT; ++kt) {
        __syncthreads();   // previous compute finished before overwrite
#pragma unroll
        for (int p = 0; p < 4; ++p)
            __builtin_amdgcn_global_load_lds(
                (const __attribute__((address_space(1))) uint32_t*)(gsrc[p] + (size_t)kt * 32),
                (__attribute__((address_space(3))) uint32_t*)ldst[p], 16, 0, 0);
        __syncthreads();   // drains vmcnt before barrier
        bf16x8 fa[4], fb[4];
#pragma unroll
        for (int i = 0; i < 4; ++i) fa[i] = *(const bf16x8*)pA[i];
#pragma unroll
        for (int j = 0; j < 4; ++j) fb[j] = *(const bf16x8*)pB[j];
#pragma unroll
        for (int i = 0; i < 4; ++i)
#pragma unroll
            for (int j = 0; j < 4; ++j)
                acc[i][j] = __builtin_amdgcn_mfma_f32_16x16x32_bf16(fb[j], fa[i], acc[i][j], 0, 0, 0);
    }

    // --- epilogue ---
#pragma unroll
    for (int i = 0; i < 4; ++i) {
        int ml = wm * 64 + i * 16 + lr;
        int gm = m0 + ml;
        bool valid = gm < ne;
        int tok = 0; float gv = 0.f;
        if (MODE == 1 && valid) { tok = tok_ids[b0 + gm]; gv = sgate[b0 + gm]; }
#pragma unroll
        for (int j = 0; j < 4; ++j) {
            int gn = n0 + wn * 64 + j * 16 + lq * 4;
            if (valid) {
                f32x4 bv = *(const f32x4*)&bias[(size_t)e * ND + gn];
                if (MODE == 0) {
                    bf16x4 hv;
#pragma unroll
                    for (int r = 0; r < 4; ++r)
                        hv[r] = (__bf16)fmaxf(acc[i][j][r] + bv[r], 0.f);
                    *(bf16x4*)&hbuf[(size_t)(b0 + gm) * HID + gn] = hv;
                } else {
#pragma unroll
                    for (int r = 0; r < 4; ++r)
                        atomicAdd(&out[(size_t)tok * OUTD + gn + r],
                                  gv * (acc[i][j][r] + bv[r]));
                }
            }
        }
    }
}

extern "C" void kernel_launch(void* const* d_in, const int* in_sizes, int n_in,
                              void* d_out, int out_size, void* d_ws, size_t ws_size,
                              hipStream_t stream) {
    const float* x  = (const float*)d_in[0];
    const float* wg = (const float*)d_in[1];
    const float* w1 = (const float*)d_in[2];
    const float* b1 = (const float*)d_in[3];
    const float* w2 = (const float*)d_in[4];
    const float* b2 = (const float*)d_in[5];
    float* out = (float*)d_out;

    char* ws = (char*)d_ws;
    size_t o = 0;
    auto alloc = [&](size_t b) { size_t r = o; o = (o + b + 255) & ~(size_t)255; return r; };
    int*    counts  = (int*)(ws + alloc(NE * 4));
    int*    cursor  = (int*)(ws + alloc(NE * 4));
    int*    bases   = (int*)(ws + alloc(NE * 4));
    float*  imp     = (float*)(ws + alloc(NE * 4));
    int*    tki     = (int*)(ws + alloc(SLOTS * 4));
    float*  tkg     = (float*)(ws + alloc(SLOTS * 4));
    int*    tok_ids = (int*)(ws + alloc(SLOTS * 4));
    float*  sgate   = (float*)(ws + alloc(SLOTS * 4));
    bf16_t* xb      = (bf16_t*)(ws + alloc((size_t)N_TOK * DIM * 2));
    bf16_t* w1t     = (bf16_t*)(ws + alloc((size_t)NE * HID * DIM * 2));
    bf16_t* w2t     = (bf16_t*)(ws + alloc((size_t)NE * OUTD * HID * 2));
    bf16_t* hbuf    = (bf16_t*)(ws + alloc((size_t)SLOTS_PAD * HID * 2));
    (void)ws_size; (void)n_in; (void)in_sizes;

    hipMemsetAsync(d_out, 0, (size_t)out_size * 4, stream);   // out must be zero (atomic accum)
    hipMemsetAsync(ws, 0, 1024, stream);                       // counts + cursor (+bases/imp, rewritten)

    k_cast_x<<<(N_TOK * DIM) / 1024, 256, 0, stream>>>(x, xb);
    k_transpose<<<dim3(HID / 32, DIM / 32, NE), dim3(32, 8), 0, stream>>>(w1, w1t, DIM, HID);
    k_transpose<<<dim3(OUTD / 32, HID / 32, NE), dim3(32, 8), 0, stream>>>(w2, w2t, HID, OUTD);
    k_gating<<<N_TOK, 64, 0, stream>>>(x, wg, tki, tkg, counts);
    k_importance<<<NE, 256, 0, stream>>>(tki, tkg, imp);
    k_finalize<<<1, 64, 0, stream>>>(imp, counts, bases, out + (size_t)N_TOK * OUTD);
    k_build<<<SLOTS / 256, 256, 0, stream>>>(tki, tkg, bases, cursor, tok_ids, sgate);

    k_gemm<0><<<dim3(HID / 128, N_TOK / 128, NE), 256, 0, stream>>>(
        xb, w1t, b1, tok_ids, sgate, bases, counts, hbuf, nullptr);
    k_gemm<1><<<dim3(OUTD / 128, N_TOK / 128, NE), 256, 0, stream>>>(
        hbuf, w2t, b2, tok_ids, sgate, bases, counts, nullptr, out);
}

// Round 2
// 569.098 us; speedup vs baseline: 1.0357x; 1.0357x over previous
//
#include <hip/hip_runtime.h>
#include <hip/hip_bf16.h>
#include <stdint.h>

#define N_TOK 4096
#define DIM   1024
#define NE    8
#define HID   4096
#define OUTD  1024
#define TOPK  2
#define SLOTS (N_TOK*TOPK)
#define SLOTS_PAD (SLOTS+128)

typedef __bf16 bf16_t;
typedef __attribute__((ext_vector_type(8))) __bf16 bf16x8;
typedef __attribute__((ext_vector_type(4))) __bf16 bf16x4;
typedef __attribute__((ext_vector_type(4))) float  f32x4;

// ---------------- gating: logits in fp64, top-2, softmax ----------------
__global__ void k_gating(const float* __restrict__ x, const float* __restrict__ wg,
                         int* __restrict__ tki, float* __restrict__ tkg,
                         int* __restrict__ counts) {
    int n = blockIdx.x;
    int lane = threadIdx.x;            // 64 threads
    double acc[NE];
#pragma unroll
    for (int e = 0; e < NE; ++e) acc[e] = 0.0;
    const float* xr = x + (size_t)n * DIM;
    for (int d = lane; d < DIM; d += 64) {
        double xv = (double)xr[d];
        const float* wr = wg + (size_t)d * NE;
#pragma unroll
        for (int e = 0; e < NE; ++e) acc[e] += xv * (double)wr[e];
    }
#pragma unroll
    for (int e = 0; e < NE; ++e)
        for (int off = 32; off > 0; off >>= 1) acc[e] += __shfl_xor(acc[e], off);
    if (lane == 0) {
        int i0 = 0; double v0 = acc[0];
#pragma unroll
        for (int e = 1; e < NE; ++e) if (acc[e] > v0) { v0 = acc[e]; i0 = e; }
        int i1 = -1; double v1 = -1e300;
#pragma unroll
        for (int e = 0; e < NE; ++e) if (e != i0 && acc[e] > v1) { v1 = acc[e]; i1 = e; }
        double e1 = exp(v1 - v0);
        double s = 1.0 + e1;
        tki[n*2]   = i0;  tki[n*2+1] = i1;
        tkg[n*2]   = (float)(1.0 / s);
        tkg[n*2+1] = (float)(e1 / s);
        atomicAdd(&counts[i0], 1);
        atomicAdd(&counts[i1], 1);
    }
}

// ---------------- importance: deterministic per-expert reduction ----------------
__global__ void k_importance(const int* __restrict__ tki, const float* __restrict__ tkg,
                             float* __restrict__ imp) {
    int e = blockIdx.x, t = threadIdx.x;
    __shared__ float red[256];
    float s = 0.f;
    for (int i = t; i < SLOTS; i += 256) s += (tki[i] == e) ? tkg[i] : 0.f;
    red[t] = s; __syncthreads();
    for (int off = 128; off > 0; off >>= 1) {
        if (t < off) red[t] += red[t + off];
        __syncthreads();
    }
    if (t == 0) imp[e] = red[0];
}

// ---------------- aux loss + prefix-sum bases ----------------
__global__ void k_finalize(const float* __restrict__ imp, const int* __restrict__ counts,
                           int* __restrict__ bases, float* __restrict__ aux_out) {
    if (threadIdx.x == 0 && blockIdx.x == 0) {
        float m = 0.f;
        for (int e = 0; e < NE; ++e) m += imp[e];
        m /= (float)NE;
        float var = 0.f;
        for (int e = 0; e < NE; ++e) { float d = imp[e] - m; var += d * d; }
        var /= (float)NE;
        aux_out[0] = 0.01f * var / (m * m + 1e-10f);
        int b = 0;
        for (int e = 0; e < NE; ++e) { bases[e] = b; b += counts[e]; }
    }
}

// ---------------- build per-expert token lists ----------------
__global__ void k_build(const int* __restrict__ tki, const float* __restrict__ tkg,
                        const int* __restrict__ bases, int* __restrict__ cursor,
                        int* __restrict__ tok_ids, float* __restrict__ sgate) {
    int i = blockIdx.x * 256 + threadIdx.x;
    if (i < SLOTS) {
        int e = tki[i];
        int p = atomicAdd(&cursor[e], 1);
        int s = bases[e] + p;
        tok_ids[s] = i >> 1;
        sgate[s]   = tkg[i];
    }
}

// ---------------- x fp32 -> bf16 ----------------
__global__ void k_cast_x(const float* __restrict__ x, bf16_t* __restrict__ xb) {
    int i = (blockIdx.x * 256 + threadIdx.x) * 4;
    float4 v = *(const float4*)(x + i);
    bf16x4 o;
    o[0] = (__bf16)v.x; o[1] = (__bf16)v.y; o[2] = (__bf16)v.z; o[3] = (__bf16)v.w;
    *(bf16x4*)(xb + i) = o;
}

// ---------------- W [E][R][C] fp32 -> Wt [E][C][R] bf16 (LDS tiled) ----------------
__global__ void k_transpose(const float* __restrict__ src, bf16_t* __restrict__ dst,
                            int R, int C) {
    __shared__ float tile[32][33];
    const size_t slab = (size_t)R * C;
    const float* s = src + slab * blockIdx.z;
    bf16_t*      d = dst + slab * blockIdx.z;
    int c0 = blockIdx.x * 32, r0 = blockIdx.y * 32;
#pragma unroll
    for (int ss = 0; ss < 32; ss += 8)
        tile[threadIdx.y + ss][threadIdx.x] =
            s[(size_t)(r0 + threadIdx.y + ss) * C + c0 + threadIdx.x];
    __syncthreads();
#pragma unroll
    for (int ss = 0; ss < 32; ss += 8)
        d[(size_t)(c0 + threadIdx.y + ss) * R + r0 + threadIdx.x] =
            (__bf16)tile[threadIdx.x][threadIdx.y + ss];
}

// ---------------- grouped GEMM, 128x128 tile, BK=32, 4 waves ----------------
// 2-phase double-buffered pipeline (T3 minimum): stage(next) -> compute(cur)
// -> one __syncthreads()/step (vmcnt(0)+barrier). XCD-aware 1D grid decode:
// one expert per XCD, y-tiles fastest -> B-panel + expert token slab L2-hot.
// MODE 0: h = relu(x_gather @ W1t^T + b1) -> hbuf (bf16)
// MODE 1: out[token] += gate * (h @ W2t^T + b2)  (atomic, exactly 2 adds/elem)
template <int MODE>
__global__ __launch_bounds__(256, 4)
void k_gemm(const bf16_t* __restrict__ A,    // MODE0: xb [N][DIM]; MODE1: hbuf [SLOTS_PAD][HID]
            const bf16_t* __restrict__ Bt,   // MODE0: w1t [E][HID][DIM]; MODE1: w2t [E][OUTD][HID]
            const float* __restrict__ bias,  // MODE0: b1 [E][HID]; MODE1: b2 [E][OUTD]
            const int* __restrict__ tok_ids,
            const float* __restrict__ sgate,
            const int* __restrict__ bases,
            const int* __restrict__ counts,
            bf16_t* __restrict__ hbuf,
            float* __restrict__ out) {
    constexpr int KD = (MODE == 0) ? DIM : HID;   // K length
    constexpr int ND = (MODE == 0) ? HID : OUTD;  // B-row count
    constexpr int NX = ND / 128;                  // n-panels per expert (32 or 8)
    constexpr int LOG_NX = (MODE == 0) ? 5 : 3;
    constexpr int BUF = 128 * 32;                 // elems per LDS buffer

    // --- XCD-aware decode: xcd = bid%8 owns expert xcd; y fastest ---
    const int g  = blockIdx.x & 7;
    const int s  = blockIdx.x >> 3;
    const int y  = s & 31;
    const int pl = s >> 5;                        // panel-local on this XCD
    const int p  = g * (NX) + pl;                 // NP/8 == NX (one expert/XCD)
    const int e  = p >> LOG_NX;
    const int xq = p & (NX - 1);

    const int ne = counts[e];
    const int m0 = y * 128;
    if (m0 >= ne) return;
    const int n0 = xq * 128;
    const int b0 = bases[e];

    __shared__ bf16_t lA[2 * BUF];  // 16 KB, XOR-swizzled slots
    __shared__ bf16_t lB[2 * BUF];  // 16 KB

    const int t    = threadIdx.x;
    const int wave = t >> 6, lane = t & 63;
    const int wm = wave >> 1, wn = wave & 1;
    const int lr = lane & 15, lq = lane >> 4;

    // --- staging setup: waves 0-1 stage A rows, waves 2-3 stage Bt rows ---
    const int tilesel = wave >> 1;
    const int half    = wave & 1;
    const bf16_t* gsrc[4];
    bf16_t*       ldst[4];
#pragma unroll
    for (int pp = 0; pp < 4; ++pp) {
        int row  = half * 64 + pp * 16 + (lane >> 2);
        int slot = lane & 3;
        int gk   = slot ^ ((row >> 1) & 3);   // logical k-group at this physical slot
        if (tilesel == 0) {
            size_t arow;
            if (MODE == 0) {
                int mm  = m0 + row;
                int tok = tok_ids[b0 + (mm < ne ? mm : 0)];
                arow = (size_t)tok * KD;
            } else {
                arow = (size_t)(b0 + m0 + row) * KD;
            }
            gsrc[pp] = A + arow + gk * 8;
            ldst[pp] = lA + (half * 64 + pp * 16) * 32;   // wave-uniform base
        } else {
            gsrc[pp] = Bt + ((size_t)e * ND + n0 + row) * KD + gk * 8;
            ldst[pp] = lB + (half * 64 + pp * 16) * 32;
        }
    }

    // --- LDS fragment read pointers (buffer 0) ---
    const bf16_t* pA[4];
    const bf16_t* pB[4];
#pragma unroll
    for (int i = 0; i < 4; ++i) {
        int r = wm * 64 + i * 16 + lr;
        pA[i] = lA + r * 32 + ((lq ^ ((r >> 1) & 3)) << 3);
    }
#pragma unroll
    for (int j = 0; j < 4; ++j) {
        int r = wn * 64 + j * 16 + lr;
        pB[j] = lB + r * 32 + ((lq ^ ((r >> 1) & 3)) << 3);
    }

    f32x4 acc[4][4];
#pragma unroll
    for (int i = 0; i < 4; ++i)
#pragma unroll
        for (int j = 0; j < 4; ++j) acc[i][j] = (f32x4){0.f, 0.f, 0.f, 0.f};

    constexpr int KT = KD / 32;

    // prologue: stage tile 0 into buffer 0, wait (vmcnt(0) + barrier)
#pragma unroll
    for (int pp = 0; pp < 4; ++pp)
        __builtin_amdgcn_global_load_lds(
            (const __attribute__((address_space(1))) uint32_t*)(gsrc[pp]),
            (__attribute__((address_space(3))) uint32_t*)(ldst[pp]), 16, 0, 0);
    __syncthreads();

    int cur = 0;
    for (int kt = 0; kt < KT; ++kt) {
        // issue next tile's loads into the other buffer (overlaps with compute)
        if (kt + 1 < KT) {
            const int nb = cur ^ 1;
#pragma unroll
            for (int pp = 0; pp < 4; ++pp)
                __builtin_amdgcn_global_load_lds(
                    (const __attribute__((address_space(1))) uint32_t*)(gsrc[pp] + (size_t)(kt + 1) * 32),
                    (__attribute__((address_space(3))) uint32_t*)(ldst[pp] + nb * BUF), 16, 0, 0);
        }
        // compute current buffer
        bf16x8 fa[4], fb[4];
#pragma unroll
        for (int i = 0; i < 4; ++i) fa[i] = *(const bf16x8*)(pA[i] + cur * BUF);
#pragma unroll
        for (int j = 0; j < 4; ++j) fb[j] = *(const bf16x8*)(pB[j] + cur * BUF);
#pragma unroll
        for (int i = 0; i < 4; ++i)
#pragma unroll
            for (int j = 0; j < 4; ++j)
                acc[i][j] = __builtin_amdgcn_mfma_f32_16x16x32_bf16(fb[j], fa[i], acc[i][j], 0, 0, 0);
        __syncthreads();   // drains vmcnt(0): next buffer ready; cur safe to overwrite
        cur ^= 1;
    }

    // --- epilogue ---
#pragma unroll
    for (int i = 0; i < 4; ++i) {
        int ml = wm * 64 + i * 16 + lr;
        int gm = m0 + ml;
        bool valid = gm < ne;
        int tok = 0; float gv = 0.f;
        if (MODE == 1 && valid) { tok = tok_ids[b0 + gm]; gv = sgate[b0 + gm]; }
#pragma unroll
        for (int j = 0; j < 4; ++j) {
            int gn = n0 + wn * 64 + j * 16 + lq * 4;
            if (valid) {
                f32x4 bv = *(const f32x4*)&bias[(size_t)e * ND + gn];
                if (MODE == 0) {
                    bf16x4 hv;
#pragma unroll
                    for (int r = 0; r < 4; ++r)
                        hv[r] = (__bf16)fmaxf(acc[i][j][r] + bv[r], 0.f);
                    *(bf16x4*)&hbuf[(size_t)(b0 + gm) * HID + gn] = hv;
                } else {
#pragma unroll
                    for (int r = 0; r < 4; ++r)
                        atomicAdd(&out[(size_t)tok * OUTD + gn + r],
                                  gv * (acc[i][j][r] + bv[r]));
                }
            }
        }
    }
}

extern "C" void kernel_launch(void* const* d_in, const int* in_sizes, int n_in,
                              void* d_out, int out_size, void* d_ws, size_t ws_size,
                              hipStream_t stream) {
    const float* x  = (const float*)d_in[0];
    const float* wg = (const float*)d_in[1];
    const float* w1 = (const float*)d_in[2];
    const float* b1 = (const float*)d_in[3];
    const float* w2 = (const float*)d_in[4];
    const float* b2 = (const float*)d_in[5];
    float* out = (float*)d_out;

    char* ws = (char*)d_ws;
    size_t o = 0;
    auto alloc = [&](size_t b) { size_t r = o; o = (o + b + 255) & ~(size_t)255; return r; };
    int*    counts  = (int*)(ws + alloc(NE * 4));
    int*    cursor  = (int*)(ws + alloc(NE * 4));
    int*    bases   = (int*)(ws + alloc(NE * 4));
    float*  imp     = (float*)(ws + alloc(NE * 4));
    int*    tki     = (int*)(ws + alloc(SLOTS * 4));
    float*  tkg     = (float*)(ws + alloc(SLOTS * 4));
    int*    tok_ids = (int*)(ws + alloc(SLOTS * 4));
    float*  sgate   = (float*)(ws + alloc(SLOTS * 4));
    bf16_t* xb      = (bf16_t*)(ws + alloc((size_t)N_TOK * DIM * 2));
    bf16_t* w1t     = (bf16_t*)(ws + alloc((size_t)NE * HID * DIM * 2));
    bf16_t* w2t     = (bf16_t*)(ws + alloc((size_t)NE * OUTD * HID * 2));
    bf16_t* hbuf    = (bf16_t*)(ws + alloc((size_t)SLOTS_PAD * HID * 2));
    (void)ws_size; (void)n_in; (void)in_sizes;

    hipMemsetAsync(d_out, 0, (size_t)out_size * 4, stream);   // out must be zero (atomic accum)
    hipMemsetAsync(ws, 0, 1024, stream);                       // counts + cursor (+bases/imp, rewritten)

    k_cast_x<<<(N_TOK * DIM) / 1024, 256, 0, stream>>>(x, xb);
    k_transpose<<<dim3(HID / 32, DIM / 32, NE), dim3(32, 8), 0, stream>>>(w1, w1t, DIM, HID);
    k_transpose<<<dim3(OUTD / 32, HID / 32, NE), dim3(32, 8), 0, stream>>>(w2, w2t, HID, OUTD);
    k_gating<<<N_TOK, 64, 0, stream>>>(x, wg, tki, tkg, counts);
    k_importance<<<NE, 256, 0, stream>>>(tki, tkg, imp);
    k_finalize<<<1, 64, 0, stream>>>(imp, counts, bases, out + (size_t)N_TOK * OUTD);
    k_build<<<SLOTS / 256, 256, 0, stream>>>(tki, tkg, bases, cursor, tok_ids, sgate);

    // 1D grids: NE*NX*NY blocks (NY=32 fixed); decode in-kernel
    k_gemm<0><<<NE * (HID / 128) * 32, 256, 0, stream>>>(
        xb, w1t, b1, tok_ids, sgate, bases, counts, hbuf, nullptr);
    k_gemm<1><<<NE * (OUTD / 128) * 32, 256, 0, stream>>>(
        hbuf, w2t, b2, tok_ids, sgate, bases, counts, nullptr, out);
}